// Round 7
// baseline (2037.502 us; speedup 1.0000x reference)
//
#include <hip/hip_runtime.h>

typedef short bf16x8 __attribute__((ext_vector_type(8)));
typedef float f32x4 __attribute__((ext_vector_type(4)));
typedef unsigned short us4 __attribute__((ext_vector_type(4)));

#define B_ 16
#define S_ 2048
#define F_ 512
#define U_ 512
#define NROWS (B_ * S_)          // 32768

#define MFMA(a, b, c) __builtin_amdgcn_mfma_f32_16x16x32_bf16((a), (b), (c), 0, 0, 0)

__device__ __forceinline__ unsigned short f2b(float f) {
    unsigned u = __builtin_bit_cast(unsigned, f);
    return (unsigned short)((u + 0x7FFFu + ((u >> 16) & 1u)) >> 16);
}

// ---------------------------------------------------------------------------
// x fp32 -> bf16 row-major [32768][512]
// ---------------------------------------------------------------------------
__global__ __launch_bounds__(256) void conv_x(const float* __restrict__ x,
                                              unsigned short* __restrict__ xb)
{
    const size_t n8 = (size_t)NROWS * F_ / 8;
    const size_t stride = (size_t)gridDim.x * 256;
    for (size_t i = (size_t)blockIdx.x * 256 + threadIdx.x; i < n8; i += stride) {
        const float4 a = ((const float4*)x)[i * 2];
        const float4 b = ((const float4*)x)[i * 2 + 1];
        us4 lo, hi;
        lo.x = f2b(a.x); lo.y = f2b(a.y); lo.z = f2b(a.z); lo.w = f2b(a.w);
        hi.x = f2b(b.x); hi.y = f2b(b.y); hi.z = f2b(b.z); hi.w = f2b(b.w);
        ((us4*)xb)[i * 2]     = lo;
        ((us4*)xb)[i * 2 + 1] = hi;
    }
}

// ---------------------------------------------------------------------------
// W [k][n] fp32 -> Wt [z][n][k] bf16 (transposed)
// ---------------------------------------------------------------------------
__global__ __launch_bounds__(256) void conv_w(const float* __restrict__ Wq,
                                              const float* __restrict__ Wk,
                                              const float* __restrict__ Wv,
                                              unsigned short* __restrict__ Wt)
{
    const float* W = (blockIdx.z == 0) ? Wq : (blockIdx.z == 1) ? Wk : Wv;
    unsigned short* out = Wt + (size_t)blockIdx.z * F_ * U_;
    __shared__ float tile[32][33];
    const int k0 = blockIdx.x * 32, n0 = blockIdx.y * 32;
    const int r = threadIdx.x >> 5, c = threadIdx.x & 31;
    #pragma unroll
    for (int p = 0; p < 4; ++p)
        tile[p * 8 + r][c] = W[(size_t)(k0 + p * 8 + r) * U_ + n0 + c];
    __syncthreads();
    #pragma unroll
    for (int p = 0; p < 4; ++p)
        out[(size_t)(n0 + p * 8 + r) * F_ + k0 + c] = f2b(tile[c][p * 8 + r]);
}

// ---------------------------------------------------------------------------
// QKV GEMM, bf16 MFMA 16x16x32.  Tile 128x64, 4 waves, BK=32.
// z=0 -> Qb (pre-scaled by 1/sqrt(512)), z=1 -> Kb, z=2 -> Vt [b][u][s].
// ---------------------------------------------------------------------------
__global__ __launch_bounds__(256) void qkv_gemm(
    const unsigned short* __restrict__ xb,
    const unsigned short* __restrict__ Wt,
    unsigned short* __restrict__ Qb,
    unsigned short* __restrict__ Kb,
    unsigned short* __restrict__ Vt)
{
    __shared__ char smem[128 * 65 * 4];                 // 33280 B
    unsigned short* Xs = (unsigned short*)smem;         // [128][32] swizzled
    unsigned short* Ws = Xs + 128 * 32;                 // [64][32]  swizzled
    float* Cs = (float*)smem;                           // [128][65]

    const int z = blockIdx.z;
    const unsigned short* Wz = Wt + (size_t)z * F_ * U_;
    const int bm = blockIdx.x * 128;
    const int bn = blockIdx.y * 64;
    const int t = threadIdx.x;
    const int w = t >> 6, l = t & 63, lr = l & 15, lg = l >> 4;
    const int vxA = (lr >> 1) & 3;       // read-side slot XOR

    f32x4 acc[2][4];
    #pragma unroll
    for (int mt = 0; mt < 2; ++mt)
        #pragma unroll
        for (int nt = 0; nt < 4; ++nt)
            acc[mt][nt] = (f32x4){0.f, 0.f, 0.f, 0.f};

    for (int kc = 0; kc < 16; ++kc) {
        const int k0 = kc * 32;
        __syncthreads();
        #pragma unroll
        for (int p = 0; p < 2; ++p) {
            const int idx = p * 256 + t;
            const int row = idx >> 2, slot = idx & 3;
            const bf16x8 v =
                *(const bf16x8*)&xb[(size_t)(bm + row) * F_ + k0 + slot * 8];
            *(bf16x8*)&Xs[row * 32 + ((slot ^ ((row >> 1) & 3)) * 8)] = v;
        }
        {
            const int row = t >> 2, slot = t & 3;
            const bf16x8 v =
                *(const bf16x8*)&Wz[(size_t)(bn + row) * F_ + k0 + slot * 8];
            *(bf16x8*)&Ws[row * 32 + ((slot ^ ((row >> 1) & 3)) * 8)] = v;
        }
        __syncthreads();
        const bf16x8 a0 = *(const bf16x8*)&Xs[(w * 32 + lr) * 32 + ((lg ^ vxA) * 8)];
        const bf16x8 a1 = *(const bf16x8*)&Xs[(w * 32 + 16 + lr) * 32 + ((lg ^ vxA) * 8)];
        #pragma unroll
        for (int nt = 0; nt < 4; ++nt) {
            const bf16x8 bb = *(const bf16x8*)&Ws[(nt * 16 + lr) * 32 + ((lg ^ vxA) * 8)];
            acc[0][nt] = MFMA(a0, bb, acc[0][nt]);
            acc[1][nt] = MFMA(a1, bb, acc[1][nt]);
        }
    }
    __syncthreads();
    #pragma unroll
    for (int mt = 0; mt < 2; ++mt)
        #pragma unroll
        for (int nt = 0; nt < 4; ++nt)
            #pragma unroll
            for (int j = 0; j < 4; ++j)
                Cs[(w * 32 + mt * 16 + lg * 4 + j) * 65 + nt * 16 + lr] = acc[mt][nt][j];
    __syncthreads();

    if (z < 2) {
        unsigned short* out = (z == 0) ? Qb : Kb;
        const float qs = (z == 0) ? 0.044194173824159216f : 1.0f;  // 1/sqrt(512)
        const int row = t >> 1, half = t & 1;
        unsigned short tmp[32];
        #pragma unroll
        for (int i = 0; i < 32; ++i) tmp[i] = f2b(Cs[row * 65 + half * 32 + i] * qs);
        #pragma unroll
        for (int v = 0; v < 4; ++v)
            *(bf16x8*)&out[(size_t)(bm + row) * U_ + bn + half * 32 + v * 8] =
                *(bf16x8*)&tmp[v * 8];
    } else {
        const int c = t >> 2, s0 = (t & 3) * 32;
        const int b = bm >> 11, sbase = (bm & 2047) + s0;
        unsigned short tmp[32];
        #pragma unroll
        for (int i = 0; i < 32; ++i) tmp[i] = f2b(Cs[(s0 + i) * 65 + c]);
        #pragma unroll
        for (int v = 0; v < 4; ++v)
            *(bf16x8*)&Vt[((size_t)(b * U_ + bn + c)) * S_ + sbase + v * 8] =
                *(bf16x8*)&tmp[v * 8];
    }
}

// ---------------------------------------------------------------------------
// Flash attention v7: 256 threads = 4 waves, ONE wave per SIMD
// (__launch_bounds__(256,1) -> 512 unified VGPR+AGPR per wave, no spill).
// Each wave owns 32 q x full 512 u: Q-frags 128 VGPR, ctx 2x32 f32x4 (AGPR).
// Per-q K/V LDS traffic halved vs R5; softmax fully wave-local (2 barriers).
// Block = 128 q -> 256 blocks (1/CU).  XCD-phased batches; reg-prefetch.
// ---------------------------------------------------------------------------
__global__ __launch_bounds__(256, 1) void attn_mfma(
    const unsigned short* __restrict__ Qb,
    const unsigned short* __restrict__ Kb,
    const unsigned short* __restrict__ Vt,
    float* __restrict__ partial)
{
    __shared__ unsigned short Ks[32 * 516];        // 33.0 KB
    __shared__ unsigned short Vs[512 * 36];        // 36.9 KB
    __shared__ unsigned short Ps[128 * 36];        //  9.2 KB
    __shared__ float SumBuf[4][512];               //  8.0 KB -> 87 KB

    const int d = blockIdx.x;                      // 0..255
    const int b    = ((d & 7) << 1) | (d >> 7);    // XCD j -> batches 2j,2j+1
    const int qblk = (d >> 3) & 15;                // 0..15
    const int t = threadIdx.x;                     // 0..255
    const int w = t >> 6;                          // 0..3
    const int l = t & 63, lr = l & 15, lg = l >> 4;

    // ---- hoist Q fragments for the wave's 32 queries ----
    bf16x8 qA[16], qB[16];
    {
        const unsigned short* qg =
            Qb + (size_t)(b * S_ + qblk * 128 + w * 32 + lr) * U_ + lg * 8;
        #pragma unroll
        for (int kc = 0; kc < 16; ++kc) {
            qA[kc] = *(const bf16x8*)(qg + kc * 32);
            qB[kc] = *(const bf16x8*)(qg + 16 * U_ + kc * 32);
        }
    }

    const unsigned short* kgb = Kb + (size_t)b * S_ * U_;
    const unsigned short* vgb = Vt + (size_t)b * U_ * S_;

    // staging: 256 threads x 16 bf16x8 covers K(32x512) + V(512x32)
    bf16x8 kreg[8], vreg[8];
    #pragma unroll
    for (int p = 0; p < 8; ++p) {
        const int id = p * 256 + t;
        kreg[p] = *(const bf16x8*)&kgb[(size_t)(id >> 6) * U_ + (id & 63) * 8];
        vreg[p] = *(const bf16x8*)&vgb[(size_t)(id >> 2) * S_ + (id & 3) * 8];
    }

    f32x4 ctxA[32], ctxB[32];
    #pragma unroll
    for (int nt = 0; nt < 32; ++nt) {
        ctxA[nt] = (f32x4){0.f, 0.f, 0.f, 0.f};
        ctxB[nt] = (f32x4){0.f, 0.f, 0.f, 0.f};
    }
    float m_a = -1e30f, m_b = -1e30f, l_a = 0.f, l_b = 0.f;

    for (int kb = 0; kb < S_ / 32; ++kb) {
        __syncthreads();                 // prev iteration done reading LDS
        #pragma unroll
        for (int p = 0; p < 8; ++p) {
            const int id = p * 256 + t;
            *(bf16x8*)&Ks[(id >> 6) * 516 + (id & 63) * 8] = kreg[p];
            *(bf16x8*)&Vs[(id >> 2) * 36 + (id & 3) * 8]   = vreg[p];
        }
        __syncthreads();                 // tiles visible

        // prefetch next tile (consumed next iteration)
        const int nkb = (kb < S_ / 32 - 1) ? kb + 1 : kb;
        #pragma unroll
        for (int p = 0; p < 8; ++p) {
            const int id = p * 256 + t;
            kreg[p] = *(const bf16x8*)&kgb[(size_t)(nkb * 32 + (id >> 6)) * U_ + (id & 63) * 8];
            vreg[p] = *(const bf16x8*)&vgb[(size_t)(id >> 2) * S_ + nkb * 32 + (id & 3) * 8];
        }

        // ---- QK^T: S^T[32 keys][32 q], K-frag read once feeds 2 q-tiles ----
        f32x4 s00 = (f32x4){0.f,0.f,0.f,0.f}, s10 = (f32x4){0.f,0.f,0.f,0.f};
        f32x4 s01 = (f32x4){0.f,0.f,0.f,0.f}, s11 = (f32x4){0.f,0.f,0.f,0.f};
        #pragma unroll
        for (int kc = 0; kc < 16; ++kc) {
            const bf16x8 kf0 = *(const bf16x8*)&Ks[lr * 516 + kc * 32 + lg * 8];
            const bf16x8 kf1 = *(const bf16x8*)&Ks[(16 + lr) * 516 + kc * 32 + lg * 8];
            s00 = MFMA(kf0, qA[kc], s00);
            s10 = MFMA(kf1, qA[kc], s10);
            s01 = MFMA(kf0, qB[kc], s01);
            s11 = MFMA(kf1, qB[kc], s11);
        }

        // ---- wave-local online softmax, deferred rescale (THR=8) ----
        float mbA = fmaxf(fmaxf(s00[0], s00[1]), fmaxf(s00[2], s00[3]));
        float mbB = fmaxf(fmaxf(s01[0], s01[1]), fmaxf(s01[2], s01[3]));
        #pragma unroll
        for (int j = 0; j < 4; ++j) {
            mbA = fmaxf(mbA, s10[j]);
            mbB = fmaxf(mbB, s11[j]);
        }
        mbA = fmaxf(mbA, __shfl_xor(mbA, 16)); mbA = fmaxf(mbA, __shfl_xor(mbA, 32));
        mbB = fmaxf(mbB, __shfl_xor(mbB, 16)); mbB = fmaxf(mbB, __shfl_xor(mbB, 32));

        const bool ok = (mbA <= m_a + 8.f) && (mbB <= m_b + 8.f);
        if (!__all(ok)) {
            const float mna = fmaxf(m_a, mbA), mnb = fmaxf(m_b, mbB);
            const float aa = __expf(m_a - mna), ab = __expf(m_b - mnb);
            float ra[4], rb[4];
            #pragma unroll
            for (int j = 0; j < 4; ++j) {
                ra[j] = __shfl(aa, (l & 48) | (lg * 4 + j));
                rb[j] = __shfl(ab, (l & 48) | (lg * 4 + j));
            }
            #pragma unroll
            for (int nt = 0; nt < 32; ++nt)
                #pragma unroll
                for (int j = 0; j < 4; ++j) {
                    ctxA[nt][j] *= ra[j];
                    ctxB[nt][j] *= rb[j];
                }
            l_a *= aa; l_b *= ab; m_a = mna; m_b = mnb;
        }

        float pA0[4], pA1[4], pB0[4], pB1[4];
        float la = 0.f, lb = 0.f;
        #pragma unroll
        for (int j = 0; j < 4; ++j) {
            pA0[j] = __expf(s00[j] - m_a); pA1[j] = __expf(s10[j] - m_a);
            pB0[j] = __expf(s01[j] - m_b); pB1[j] = __expf(s11[j] - m_b);
            la += pA0[j] + pA1[j];
            lb += pB0[j] + pB1[j];
        }
        la += __shfl_xor(la, 16); la += __shfl_xor(la, 32);
        lb += __shfl_xor(lb, 16); lb += __shfl_xor(lb, 32);
        l_a += la; l_b += lb;

        // ---- P -> A-fragment layout via wave-private LDS rows ----
        us4 wA0, wA1, wB0, wB1;
        wA0.x = f2b(pA0[0]); wA0.y = f2b(pA0[1]); wA0.z = f2b(pA0[2]); wA0.w = f2b(pA0[3]);
        wA1.x = f2b(pA1[0]); wA1.y = f2b(pA1[1]); wA1.z = f2b(pA1[2]); wA1.w = f2b(pA1[3]);
        wB0.x = f2b(pB0[0]); wB0.y = f2b(pB0[1]); wB0.z = f2b(pB0[2]); wB0.w = f2b(pB0[3]);
        wB1.x = f2b(pB1[0]); wB1.y = f2b(pB1[1]); wB1.z = f2b(pB1[2]); wB1.w = f2b(pB1[3]);
        *(us4*)&Ps[(w * 32 + lr) * 36 + lg * 4]           = wA0;
        *(us4*)&Ps[(w * 32 + lr) * 36 + 16 + lg * 4]      = wA1;
        *(us4*)&Ps[(w * 32 + 16 + lr) * 36 + lg * 4]      = wB0;
        *(us4*)&Ps[(w * 32 + 16 + lr) * 36 + 16 + lg * 4] = wB1;
        const bf16x8 pfA = *(const bf16x8*)&Ps[(w * 32 + lr) * 36 + lg * 8];
        const bf16x8 pfB = *(const bf16x8*)&Ps[(w * 32 + 16 + lr) * 36 + lg * 8];

        // ---- PV: ctx[32 q x 512 u], V-frag read once feeds 2 q-tiles ----
        #pragma unroll
        for (int nt = 0; nt < 32; ++nt) {
            const bf16x8 vf = *(const bf16x8*)&Vs[(nt * 16 + lr) * 36 + lg * 8];
            ctxA[nt] = MFMA(pfA, vf, ctxA[nt]);
            ctxB[nt] = MFMA(pfB, vf, ctxB[nt]);
        }
    }

    // ---- epilogue: normalize, sum wave's 32 q, combine 4 waves ----
    const float invA = 1.f / l_a, invB = 1.f / l_b;
    float invrA[4], invrB[4];
    #pragma unroll
    for (int j = 0; j < 4; ++j) {
        invrA[j] = __shfl(invA, (l & 48) | (lg * 4 + j));
        invrB[j] = __shfl(invB, (l & 48) | (lg * 4 + j));
    }

    #pragma unroll
    for (int nt = 0; nt < 32; ++nt) {
        float s = ctxA[nt][0] * invrA[0] + ctxA[nt][1] * invrA[1]
                + ctxA[nt][2] * invrA[2] + ctxA[nt][3] * invrA[3]
                + ctxB[nt][0] * invrB[0] + ctxB[nt][1] * invrB[1]
                + ctxB[nt][2] * invrB[2] + ctxB[nt][3] * invrB[3];
        s += __shfl_xor(s, 16);
        s += __shfl_xor(s, 32);
        if (lg == 0) SumBuf[w][nt * 16 + lr] = s;
    }
    __syncthreads();
    for (int u = t; u < 512; u += 256) {
        const float s = SumBuf[0][u] + SumBuf[1][u] + SumBuf[2][u] + SumBuf[3][u];
        partial[(size_t)(b * 16 + qblk) * U_ + u] = s;
    }
}

// ---------------------------------------------------------------------------
// partial [16][16][512] -> out [16][512], mean over S
// ---------------------------------------------------------------------------
__global__ __launch_bounds__(256) void reduce_mean(
    const float* __restrict__ partial, float* __restrict__ out)
{
    const int b = blockIdx.x;
    for (int u = threadIdx.x; u < U_; u += 256) {
        float s = 0.f;
        #pragma unroll
        for (int p = 0; p < 16; ++p)
            s += partial[(size_t)(b * 16 + p) * U_ + u];
        out[b * U_ + u] = s * (1.0f / (float)S_);
    }
}

extern "C" void kernel_launch(void* const* d_in, const int* in_sizes, int n_in,
                              void* d_out, int out_size, void* d_ws, size_t ws_size,
                              hipStream_t stream)
{
    const float* x  = (const float*)d_in[0];
    const float* Wq = (const float*)d_in[1];
    const float* Wk = (const float*)d_in[2];
    const float* Wv = (const float*)d_in[3];
    float* out = (float*)d_out;

    unsigned short* ws = (unsigned short*)d_ws;
    const size_t XB_OFF = 0;                               // [32768][512] bf16
    const size_t WT_OFF = XB_OFF + (size_t)NROWS * F_;     // 3x[512][512] bf16
    const size_t QB_OFF = WT_OFF + 3ull * F_ * U_;
    const size_t KB_OFF = QB_OFF + (size_t)NROWS * U_;
    const size_t VT_OFF = KB_OFF + (size_t)NROWS * U_;
    const size_t END_USH = VT_OFF + (size_t)NROWS * U_;
    float* partial = (float*)(ws + END_USH);               // [16][16][512] fp32
    const size_t need = END_USH * 2 + (size_t)B_ * 16 * U_ * 4;
    if (ws_size < need) return;

    unsigned short* xb = ws + XB_OFF;
    unsigned short* Wt = ws + WT_OFF;
    unsigned short* Qb = ws + QB_OFF;
    unsigned short* Kb = ws + KB_OFF;
    unsigned short* Vt = ws + VT_OFF;

    conv_x<<<2048, 256, 0, stream>>>(x, xb);
    conv_w<<<dim3(16, 16, 3), 256, 0, stream>>>(Wq, Wk, Wv, Wt);
    qkv_gemm<<<dim3(NROWS / 128, U_ / 64, 3), 256, 0, stream>>>(xb, Wt, Qb, Kb, Vt);
    attn_mfma<<<256, 256, 0, stream>>>(Qb, Kb, Vt, partial);
    reduce_mean<<<B_, 256, 0, stream>>>(partial, out);
}

// Round 8
// 834.847 us; speedup vs baseline: 2.4406x; 2.4406x over previous
//
#include <hip/hip_runtime.h>

typedef short bf16x8 __attribute__((ext_vector_type(8)));
typedef float f32x4 __attribute__((ext_vector_type(4)));
typedef unsigned short us4 __attribute__((ext_vector_type(4)));

#define B_ 16
#define S_ 2048
#define F_ 512
#define U_ 512
#define NROWS (B_ * S_)          // 32768

#define MFMA(a, b, c) __builtin_amdgcn_mfma_f32_16x16x32_bf16((a), (b), (c), 0, 0, 0)

__device__ __forceinline__ unsigned short f2b(float f) {
    unsigned u = __builtin_bit_cast(unsigned, f);
    return (unsigned short)((u + 0x7FFFu + ((u >> 16) & 1u)) >> 16);
}

// ---------------------------------------------------------------------------
// x fp32 -> bf16 row-major [32768][512]
// ---------------------------------------------------------------------------
__global__ __launch_bounds__(256) void conv_x(const float* __restrict__ x,
                                              unsigned short* __restrict__ xb)
{
    const size_t n8 = (size_t)NROWS * F_ / 8;
    const size_t stride = (size_t)gridDim.x * 256;
    for (size_t i = (size_t)blockIdx.x * 256 + threadIdx.x; i < n8; i += stride) {
        const float4 a = ((const float4*)x)[i * 2];
        const float4 b = ((const float4*)x)[i * 2 + 1];
        us4 lo, hi;
        lo.x = f2b(a.x); lo.y = f2b(a.y); lo.z = f2b(a.z); lo.w = f2b(a.w);
        hi.x = f2b(b.x); hi.y = f2b(b.y); hi.z = f2b(b.z); hi.w = f2b(b.w);
        ((us4*)xb)[i * 2]     = lo;
        ((us4*)xb)[i * 2 + 1] = hi;
    }
}

// ---------------------------------------------------------------------------
// W [k][n] fp32 -> Wt [z][n][k] bf16 (transposed)
// ---------------------------------------------------------------------------
__global__ __launch_bounds__(256) void conv_w(const float* __restrict__ Wq,
                                              const float* __restrict__ Wk,
                                              const float* __restrict__ Wv,
                                              unsigned short* __restrict__ Wt)
{
    const float* W = (blockIdx.z == 0) ? Wq : (blockIdx.z == 1) ? Wk : Wv;
    unsigned short* out = Wt + (size_t)blockIdx.z * F_ * U_;
    __shared__ float tile[32][33];
    const int k0 = blockIdx.x * 32, n0 = blockIdx.y * 32;
    const int r = threadIdx.x >> 5, c = threadIdx.x & 31;
    #pragma unroll
    for (int p = 0; p < 4; ++p)
        tile[p * 8 + r][c] = W[(size_t)(k0 + p * 8 + r) * U_ + n0 + c];
    __syncthreads();
    #pragma unroll
    for (int p = 0; p < 4; ++p)
        out[(size_t)(n0 + p * 8 + r) * F_ + k0 + c] = f2b(tile[c][p * 8 + r]);
}

// ---------------------------------------------------------------------------
// QKV GEMM, bf16 MFMA 16x16x32.  Tile 128x64, 4 waves, BK=32.
// z=0 -> Qb (pre-scaled by 1/sqrt(512)), z=1 -> Kb, z=2 -> Vt [b][u][s].
// ---------------------------------------------------------------------------
__global__ __launch_bounds__(256) void qkv_gemm(
    const unsigned short* __restrict__ xb,
    const unsigned short* __restrict__ Wt,
    unsigned short* __restrict__ Qb,
    unsigned short* __restrict__ Kb,
    unsigned short* __restrict__ Vt)
{
    __shared__ char smem[128 * 65 * 4];                 // 33280 B
    unsigned short* Xs = (unsigned short*)smem;         // [128][32] swizzled
    unsigned short* Ws = Xs + 128 * 32;                 // [64][32]  swizzled
    float* Cs = (float*)smem;                           // [128][65]

    const int z = blockIdx.z;
    const unsigned short* Wz = Wt + (size_t)z * F_ * U_;
    const int bm = blockIdx.x * 128;
    const int bn = blockIdx.y * 64;
    const int t = threadIdx.x;
    const int w = t >> 6, l = t & 63, lr = l & 15, lg = l >> 4;
    const int vxA = (lr >> 1) & 3;       // read-side slot XOR

    f32x4 acc[2][4];
    #pragma unroll
    for (int mt = 0; mt < 2; ++mt)
        #pragma unroll
        for (int nt = 0; nt < 4; ++nt)
            acc[mt][nt] = (f32x4){0.f, 0.f, 0.f, 0.f};

    for (int kc = 0; kc < 16; ++kc) {
        const int k0 = kc * 32;
        __syncthreads();
        #pragma unroll
        for (int p = 0; p < 2; ++p) {
            const int idx = p * 256 + t;
            const int row = idx >> 2, slot = idx & 3;
            const bf16x8 v =
                *(const bf16x8*)&xb[(size_t)(bm + row) * F_ + k0 + slot * 8];
            *(bf16x8*)&Xs[row * 32 + ((slot ^ ((row >> 1) & 3)) * 8)] = v;
        }
        {
            const int row = t >> 2, slot = t & 3;
            const bf16x8 v =
                *(const bf16x8*)&Wz[(size_t)(bn + row) * F_ + k0 + slot * 8];
            *(bf16x8*)&Ws[row * 32 + ((slot ^ ((row >> 1) & 3)) * 8)] = v;
        }
        __syncthreads();
        const bf16x8 a0 = *(const bf16x8*)&Xs[(w * 32 + lr) * 32 + ((lg ^ vxA) * 8)];
        const bf16x8 a1 = *(const bf16x8*)&Xs[(w * 32 + 16 + lr) * 32 + ((lg ^ vxA) * 8)];
        #pragma unroll
        for (int nt = 0; nt < 4; ++nt) {
            const bf16x8 bb = *(const bf16x8*)&Ws[(nt * 16 + lr) * 32 + ((lg ^ vxA) * 8)];
            acc[0][nt] = MFMA(a0, bb, acc[0][nt]);
            acc[1][nt] = MFMA(a1, bb, acc[1][nt]);
        }
    }
    __syncthreads();
    #pragma unroll
    for (int mt = 0; mt < 2; ++mt)
        #pragma unroll
        for (int nt = 0; nt < 4; ++nt)
            #pragma unroll
            for (int j = 0; j < 4; ++j)
                Cs[(w * 32 + mt * 16 + lg * 4 + j) * 65 + nt * 16 + lr] = acc[mt][nt][j];
    __syncthreads();

    if (z < 2) {
        unsigned short* out = (z == 0) ? Qb : Kb;
        const float qs = (z == 0) ? 0.044194173824159216f : 1.0f;  // 1/sqrt(512)
        const int row = t >> 1, half = t & 1;
        unsigned short tmp[32];
        #pragma unroll
        for (int i = 0; i < 32; ++i) tmp[i] = f2b(Cs[row * 65 + half * 32 + i] * qs);
        #pragma unroll
        for (int v = 0; v < 4; ++v)
            *(bf16x8*)&out[(size_t)(bm + row) * U_ + bn + half * 32 + v * 8] =
                *(bf16x8*)&tmp[v * 8];
    } else {
        const int c = t >> 2, s0 = (t & 3) * 32;
        const int b = bm >> 11, sbase = (bm & 2047) + s0;
        unsigned short tmp[32];
        #pragma unroll
        for (int i = 0; i < 32; ++i) tmp[i] = f2b(Cs[(s0 + i) * 65 + c]);
        #pragma unroll
        for (int v = 0; v < 4; ++v)
            *(bf16x8*)&Vt[((size_t)(b * U_ + bn + c)) * S_ + sbase + v * 8] =
                *(bf16x8*)&tmp[v * 8];
    }
}

// ---------------------------------------------------------------------------
// Flash attention v8 = R5 structure + double-buffered LDS (ONE barrier/iter)
// + s_setprio around MFMA clusters.  512 threads = 8 independent q-waves,
// each 16 q x full 512 u (ctx 32 f32x4, proven no-spill).  256 blocks, 1/CU.
// Pipeline: iter kb writes tile(kb+1) regs->back buffer (overlaps compute of
// front buffer), issues global loads for tile(kb+2), computes, 1 barrier.
// ---------------------------------------------------------------------------
__global__ __launch_bounds__(512, 2) void attn_mfma(
    const unsigned short* __restrict__ Qb,
    const unsigned short* __restrict__ Kb,
    const unsigned short* __restrict__ Vt,
    float* __restrict__ partial)
{
    __shared__ unsigned short Ks[2][32 * 516];     // 66.0 KB
    __shared__ unsigned short Vs[2][512 * 36];     // 73.7 KB
    __shared__ unsigned short Ps[128 * 36];        //  9.2 KB  -> 148.9 KB

    const int d = blockIdx.x;                      // 0..255
    const int b    = ((d & 7) << 1) | (d >> 7);    // XCD j -> batches 2j,2j+1
    const int qblk = (d >> 3) & 15;                // 0..15
    const int t = threadIdx.x;
    const int w = t >> 6;                          // 0..7 : q-wave id
    const int l = t & 63, lr = l & 15, lg = l >> 4;

    // ---- hoist Q fragments (pre-scaled by 1/sqrt(512)) ----
    bf16x8 q[16];
    {
        const unsigned short* qg =
            Qb + (size_t)(b * S_ + qblk * 128 + w * 16 + lr) * U_ + lg * 8;
        #pragma unroll
        for (int kc = 0; kc < 16; ++kc)
            q[kc] = *(const bf16x8*)(qg + kc * 32);
    }

    const unsigned short* kgb = Kb + (size_t)b * S_ * U_;
    const unsigned short* vgb = Vt + (size_t)b * U_ * S_;

    bf16x8 kreg[4], vreg[4];
    // prologue: tile 0 -> regs -> buf0; then tile 1 -> regs
    #pragma unroll
    for (int p = 0; p < 4; ++p) {
        const int id = p * 512 + t;
        kreg[p] = *(const bf16x8*)&kgb[(size_t)(id >> 6) * U_ + (id & 63) * 8];
        vreg[p] = *(const bf16x8*)&vgb[(size_t)(id >> 2) * S_ + (id & 3) * 8];
    }
    #pragma unroll
    for (int p = 0; p < 4; ++p) {
        const int id = p * 512 + t;
        *(bf16x8*)&Ks[0][(id >> 6) * 516 + (id & 63) * 8] = kreg[p];
        *(bf16x8*)&Vs[0][(id >> 2) * 36 + (id & 3) * 8]   = vreg[p];
    }
    #pragma unroll
    for (int p = 0; p < 4; ++p) {
        const int id = p * 512 + t;
        kreg[p] = *(const bf16x8*)&kgb[(size_t)(32 + (id >> 6)) * U_ + (id & 63) * 8];
        vreg[p] = *(const bf16x8*)&vgb[(size_t)(id >> 2) * S_ + 32 + (id & 3) * 8];
    }
    __syncthreads();                     // buf0 visible

    f32x4 ctx[32];
    #pragma unroll
    for (int nt = 0; nt < 32; ++nt) ctx[nt] = (f32x4){0.f, 0.f, 0.f, 0.f};
    float m_i = -1e30f, l_i = 0.f;

    int cur = 0;
    for (int kb = 0; kb < S_ / 32; ++kb) {
        // ---- publish tile(kb+1) into back buffer (overlaps compute) ----
        #pragma unroll
        for (int p = 0; p < 4; ++p) {
            const int id = p * 512 + t;
            *(bf16x8*)&Ks[cur ^ 1][(id >> 6) * 516 + (id & 63) * 8] = kreg[p];
            *(bf16x8*)&Vs[cur ^ 1][(id >> 2) * 36 + (id & 3) * 8]   = vreg[p];
        }
        // ---- issue global loads for tile(kb+2) ----
        const int nkb = (kb + 2 < S_ / 32) ? kb + 2 : S_ / 32 - 1;
        #pragma unroll
        for (int p = 0; p < 4; ++p) {
            const int id = p * 512 + t;
            kreg[p] = *(const bf16x8*)&kgb[(size_t)(nkb * 32 + (id >> 6)) * U_ + (id & 63) * 8];
            vreg[p] = *(const bf16x8*)&vgb[(size_t)(id >> 2) * S_ + nkb * 32 + (id & 3) * 8];
        }

        // ---- QK^T (swapped): S^T[key][q] from front buffer ----
        f32x4 s0 = (f32x4){0.f, 0.f, 0.f, 0.f};
        f32x4 s1 = (f32x4){0.f, 0.f, 0.f, 0.f};
        __builtin_amdgcn_s_setprio(1);
        #pragma unroll
        for (int kc = 0; kc < 16; ++kc) {
            const bf16x8 k0 = *(const bf16x8*)&Ks[cur][lr * 516 + kc * 32 + lg * 8];
            const bf16x8 k1 = *(const bf16x8*)&Ks[cur][(16 + lr) * 516 + kc * 32 + lg * 8];
            s0 = MFMA(k0, q[kc], s0);
            s1 = MFMA(k1, q[kc], s1);
        }
        __builtin_amdgcn_s_setprio(0);

        // ---- online softmax with deferred rescale (THR=8) ----
        float mb = s0[0];
        #pragma unroll
        for (int j = 1; j < 4; ++j) mb = fmaxf(mb, s0[j]);
        #pragma unroll
        for (int j = 0; j < 4; ++j) mb = fmaxf(mb, s1[j]);
        mb = fmaxf(mb, __shfl_xor(mb, 16));
        mb = fmaxf(mb, __shfl_xor(mb, 32));

        if (!__all(mb <= m_i + 8.f)) {
            const float m_new = fmaxf(m_i, mb);
            const float alpha = __expf(m_i - m_new);
            float arow[4];
            #pragma unroll
            for (int j = 0; j < 4; ++j)
                arow[j] = __shfl(alpha, (l & 48) | (lg * 4 + j));
            #pragma unroll
            for (int nt = 0; nt < 32; ++nt)
                #pragma unroll
                for (int j = 0; j < 4; ++j) ctx[nt][j] *= arow[j];
            l_i *= alpha;
            m_i = m_new;
        }

        float p0[4], p1[4];
        float ladd = 0.f;
        #pragma unroll
        for (int j = 0; j < 4; ++j) {
            p0[j] = __expf(s0[j] - m_i);
            p1[j] = __expf(s1[j] - m_i);
            ladd += p0[j] + p1[j];
        }
        ladd += __shfl_xor(ladd, 16);
        ladd += __shfl_xor(ladd, 32);
        l_i += ladd;

        // ---- P -> A-fragment layout via wave-private LDS rows ----
        us4 w0, w1;
        w0.x = f2b(p0[0]); w0.y = f2b(p0[1]); w0.z = f2b(p0[2]); w0.w = f2b(p0[3]);
        w1.x = f2b(p1[0]); w1.y = f2b(p1[1]); w1.z = f2b(p1[2]); w1.w = f2b(p1[3]);
        *(us4*)&Ps[(w * 16 + lr) * 36 + lg * 4]      = w0;
        *(us4*)&Ps[(w * 16 + lr) * 36 + 16 + lg * 4] = w1;
        const bf16x8 pf = *(const bf16x8*)&Ps[(w * 16 + lr) * 36 + lg * 8];

        // ---- PV over full 512 u ----
        __builtin_amdgcn_s_setprio(1);
        #pragma unroll
        for (int nt = 0; nt < 32; ++nt) {
            const bf16x8 vf = *(const bf16x8*)&Vs[cur][(nt * 16 + lr) * 36 + lg * 8];
            ctx[nt] = MFMA(pf, vf, ctx[nt]);
        }
        __builtin_amdgcn_s_setprio(0);

        __syncthreads();                 // single barrier: back buffer ready,
        cur ^= 1;                        // front buffer free for overwrite
    }

    // ---- epilogue: normalize, sum wave's 16 queries, combine 8 waves ----
    const float inv = 1.f / l_i;
    float invr[4];
    #pragma unroll
    for (int j = 0; j < 4; ++j)
        invr[j] = __shfl(inv, (l & 48) | (lg * 4 + j));

    float* SumBuf = (float*)&Ks[0][0];     // alias (loop done): [8][512] fp32
    #pragma unroll
    for (int nt = 0; nt < 32; ++nt) {
        float s = ctx[nt][0] * invr[0] + ctx[nt][1] * invr[1]
                + ctx[nt][2] * invr[2] + ctx[nt][3] * invr[3];
        s += __shfl_xor(s, 16);
        s += __shfl_xor(s, 32);
        if (lg == 0) SumBuf[w * 512 + nt * 16 + lr] = s;
    }
    __syncthreads();
    {
        const int u = t;                       // 512 threads cover 512 u
        float s = 0.f;
        #pragma unroll
        for (int ww = 0; ww < 8; ++ww) s += SumBuf[ww * 512 + u];
        partial[(size_t)(b * 16 + qblk) * U_ + u] = s;
    }
}

// ---------------------------------------------------------------------------
// partial [16][16][512] -> out [16][512], mean over S
// ---------------------------------------------------------------------------
__global__ __launch_bounds__(256) void reduce_mean(
    const float* __restrict__ partial, float* __restrict__ out)
{
    const int b = blockIdx.x;
    for (int u = threadIdx.x; u < U_; u += 256) {
        float s = 0.f;
        #pragma unroll
        for (int p = 0; p < 16; ++p)
            s += partial[(size_t)(b * 16 + p) * U_ + u];
        out[b * U_ + u] = s * (1.0f / (float)S_);
    }
}

extern "C" void kernel_launch(void* const* d_in, const int* in_sizes, int n_in,
                              void* d_out, int out_size, void* d_ws, size_t ws_size,
                              hipStream_t stream)
{
    const float* x  = (const float*)d_in[0];
    const float* Wq = (const float*)d_in[1];
    const float* Wk = (const float*)d_in[2];
    const float* Wv = (const float*)d_in[3];
    float* out = (float*)d_out;

    unsigned short* ws = (unsigned short*)d_ws;
    const size_t XB_OFF = 0;                               // [32768][512] bf16
    const size_t WT_OFF = XB_OFF + (size_t)NROWS * F_;     // 3x[512][512] bf16
    const size_t QB_OFF = WT_OFF + 3ull * F_ * U_;
    const size_t KB_OFF = QB_OFF + (size_t)NROWS * U_;
    const size_t VT_OFF = KB_OFF + (size_t)NROWS * U_;
    const size_t END_USH = VT_OFF + (size_t)NROWS * U_;
    float* partial = (float*)(ws + END_USH);               // [16][16][512] fp32
    const size_t need = END_USH * 2 + (size_t)B_ * 16 * U_ * 4;
    if (ws_size < need) return;

    unsigned short* xb = ws + XB_OFF;
    unsigned short* Wt = ws + WT_OFF;
    unsigned short* Qb = ws + QB_OFF;
    unsigned short* Kb = ws + KB_OFF;
    unsigned short* Vt = ws + VT_OFF;

    conv_x<<<2048, 256, 0, stream>>>(x, xb);
    conv_w<<<dim3(16, 16, 3), 256, 0, stream>>>(Wq, Wk, Wv, Wt);
    qkv_gemm<<<dim3(NROWS / 128, U_ / 64, 3), 256, 0, stream>>>(xb, Wt, Qb, Kb, Vt);
    attn_mfma<<<256, 512, 0, stream>>>(Qb, Kb, Vt, partial);
    reduce_mean<<<B_, 256, 0, stream>>>(partial, out);
}

// Round 9
// 565.361 us; speedup vs baseline: 3.6039x; 1.4767x over previous
//
#include <hip/hip_runtime.h>

typedef short bf16x8 __attribute__((ext_vector_type(8)));
typedef float f32x4 __attribute__((ext_vector_type(4)));
typedef unsigned short us4 __attribute__((ext_vector_type(4)));

#define B_ 16
#define S_ 2048
#define F_ 512
#define U_ 512
#define NROWS (B_ * S_)          // 32768

#define MFMA(a, b, c) __builtin_amdgcn_mfma_f32_16x16x32_bf16((a), (b), (c), 0, 0, 0)

// async global->LDS, 16B per lane; LDS dest = uniform base + lane*16
#define GL16(g, s) __builtin_amdgcn_global_load_lds( \
    (const __attribute__((address_space(1))) unsigned int*)(g), \
    (__attribute__((address_space(3))) unsigned int*)(s), 16, 0, 0)

__device__ __forceinline__ unsigned short f2b(float f) {
    unsigned u = __builtin_bit_cast(unsigned, f);
    return (unsigned short)((u + 0x7FFFu + ((u >> 16) & 1u)) >> 16);
}

// ---------------------------------------------------------------------------
// x fp32 -> bf16 row-major [32768][512]
// ---------------------------------------------------------------------------
__global__ __launch_bounds__(256) void conv_x(const float* __restrict__ x,
                                              unsigned short* __restrict__ xb)
{
    const size_t n8 = (size_t)NROWS * F_ / 8;
    const size_t stride = (size_t)gridDim.x * 256;
    for (size_t i = (size_t)blockIdx.x * 256 + threadIdx.x; i < n8; i += stride) {
        const float4 a = ((const float4*)x)[i * 2];
        const float4 b = ((const float4*)x)[i * 2 + 1];
        us4 lo, hi;
        lo.x = f2b(a.x); lo.y = f2b(a.y); lo.z = f2b(a.z); lo.w = f2b(a.w);
        hi.x = f2b(b.x); hi.y = f2b(b.y); hi.z = f2b(b.z); hi.w = f2b(b.w);
        ((us4*)xb)[i * 2]     = lo;
        ((us4*)xb)[i * 2 + 1] = hi;
    }
}

// ---------------------------------------------------------------------------
// W [k][n] fp32 -> Wt [z][n][k] bf16 (transposed)
// ---------------------------------------------------------------------------
__global__ __launch_bounds__(256) void conv_w(const float* __restrict__ Wq,
                                              const float* __restrict__ Wk,
                                              const float* __restrict__ Wv,
                                              unsigned short* __restrict__ Wt)
{
    const float* W = (blockIdx.z == 0) ? Wq : (blockIdx.z == 1) ? Wk : Wv;
    unsigned short* out = Wt + (size_t)blockIdx.z * F_ * U_;
    __shared__ float tile[32][33];
    const int k0 = blockIdx.x * 32, n0 = blockIdx.y * 32;
    const int r = threadIdx.x >> 5, c = threadIdx.x & 31;
    #pragma unroll
    for (int p = 0; p < 4; ++p)
        tile[p * 8 + r][c] = W[(size_t)(k0 + p * 8 + r) * U_ + n0 + c];
    __syncthreads();
    #pragma unroll
    for (int p = 0; p < 4; ++p)
        out[(size_t)(n0 + p * 8 + r) * F_ + k0 + c] = f2b(tile[c][p * 8 + r]);
}

// ---------------------------------------------------------------------------
// QKV GEMM, bf16 MFMA 16x16x32.  Tile 128x64, 4 waves, BK=32.
// z=0 -> Qb (pre-scaled by 1/sqrt(512)), z=1 -> Kb row-major,
// z=2 -> Vt TILE-layout [b][tile=s/32][u][32 k] with slot XOR pre-swizzle
//        (slot' = slot ^ ((u>>1)&3)) so attention can DMA it linearly.
// ---------------------------------------------------------------------------
__global__ __launch_bounds__(256) void qkv_gemm(
    const unsigned short* __restrict__ xb,
    const unsigned short* __restrict__ Wt,
    unsigned short* __restrict__ Qb,
    unsigned short* __restrict__ Kb,
    unsigned short* __restrict__ Vt)
{
    __shared__ char smem[128 * 65 * 4];                 // 33280 B
    unsigned short* Xs = (unsigned short*)smem;         // [128][32] swizzled
    unsigned short* Ws = Xs + 128 * 32;                 // [64][32]  swizzled
    float* Cs = (float*)smem;                           // [128][65]

    const int z = blockIdx.z;
    const unsigned short* Wz = Wt + (size_t)z * F_ * U_;
    const int bm = blockIdx.x * 128;
    const int bn = blockIdx.y * 64;
    const int t = threadIdx.x;
    const int w = t >> 6, l = t & 63, lr = l & 15, lg = l >> 4;
    const int vxA = (lr >> 1) & 3;       // read-side slot XOR

    f32x4 acc[2][4];
    #pragma unroll
    for (int mt = 0; mt < 2; ++mt)
        #pragma unroll
        for (int nt = 0; nt < 4; ++nt)
            acc[mt][nt] = (f32x4){0.f, 0.f, 0.f, 0.f};

    for (int kc = 0; kc < 16; ++kc) {
        const int k0 = kc * 32;
        __syncthreads();
        #pragma unroll
        for (int p = 0; p < 2; ++p) {
            const int idx = p * 256 + t;
            const int row = idx >> 2, slot = idx & 3;
            const bf16x8 v =
                *(const bf16x8*)&xb[(size_t)(bm + row) * F_ + k0 + slot * 8];
            *(bf16x8*)&Xs[row * 32 + ((slot ^ ((row >> 1) & 3)) * 8)] = v;
        }
        {
            const int row = t >> 2, slot = t & 3;
            const bf16x8 v =
                *(const bf16x8*)&Wz[(size_t)(bn + row) * F_ + k0 + slot * 8];
            *(bf16x8*)&Ws[row * 32 + ((slot ^ ((row >> 1) & 3)) * 8)] = v;
        }
        __syncthreads();
        const bf16x8 a0 = *(const bf16x8*)&Xs[(w * 32 + lr) * 32 + ((lg ^ vxA) * 8)];
        const bf16x8 a1 = *(const bf16x8*)&Xs[(w * 32 + 16 + lr) * 32 + ((lg ^ vxA) * 8)];
        #pragma unroll
        for (int nt = 0; nt < 4; ++nt) {
            const bf16x8 bb = *(const bf16x8*)&Ws[(nt * 16 + lr) * 32 + ((lg ^ vxA) * 8)];
            acc[0][nt] = MFMA(a0, bb, acc[0][nt]);
            acc[1][nt] = MFMA(a1, bb, acc[1][nt]);
        }
    }
    __syncthreads();
    #pragma unroll
    for (int mt = 0; mt < 2; ++mt)
        #pragma unroll
        for (int nt = 0; nt < 4; ++nt)
            #pragma unroll
            for (int j = 0; j < 4; ++j)
                Cs[(w * 32 + mt * 16 + lg * 4 + j) * 65 + nt * 16 + lr] = acc[mt][nt][j];
    __syncthreads();

    if (z < 2) {
        unsigned short* out = (z == 0) ? Qb : Kb;
        const float qs = (z == 0) ? 0.044194173824159216f : 1.0f;  // 1/sqrt(512)
        const int row = t >> 1, half = t & 1;
        unsigned short tmp[32];
        #pragma unroll
        for (int i = 0; i < 32; ++i) tmp[i] = f2b(Cs[row * 65 + half * 32 + i] * qs);
        #pragma unroll
        for (int v = 0; v < 4; ++v)
            *(bf16x8*)&out[(size_t)(bm + row) * U_ + bn + half * 32 + v * 8] =
                *(bf16x8*)&tmp[v * 8];
    } else {
        // V tile-layout write: Vt[b][tile][u][32], slot XOR pre-swizzled
        const int c = t >> 2, s0 = (t & 3) * 32;       // s0 multiple of 32
        const int b = bm >> 11, sbase = (bm & 2047) + s0;
        const int u = bn + c;
        const int tile = sbase >> 5;
        const int vx = (u >> 1) & 3;
        unsigned short tmp[32];
        #pragma unroll
        for (int i = 0; i < 32; ++i) tmp[i] = f2b(Cs[(s0 + i) * 65 + c]);
        unsigned short* vdst =
            Vt + (size_t)b * U_ * S_ + (size_t)tile * (512 * 32) + u * 32;
        #pragma unroll
        for (int v = 0; v < 4; ++v)
            *(bf16x8*)&vdst[(v ^ vx) * 8] = *(bf16x8*)&tmp[v * 8];
    }
}

// ---------------------------------------------------------------------------
// Flash attention v9 = R5 wave structure (8 independent q-waves, 16q x 512u,
// ctx 32 f32x4) + global_load_lds DMA double-buffer, ONE raw barrier/iter:
//   stage(kb+1 -> back buffer)  [async DMA, no VGPRs]
//   compute tile kb from front buffer
//   s_waitcnt vmcnt(0); s_barrier
// K rows 1024B contiguous (pad between rows OK for DMA); V tile-contiguous
// with pre-swizzled slots (swizzle applied on read: lg ^ ((lr>>1)&3)).
// ---------------------------------------------------------------------------
__global__ __launch_bounds__(512, 2) void attn_mfma(
    const unsigned short* __restrict__ Qb,
    const unsigned short* __restrict__ Kb,
    const unsigned short* __restrict__ Vt,
    float* __restrict__ partial)
{
    __shared__ unsigned short Ks[2][32 * 516];     // 66.0 KB (rows 1032B)
    __shared__ unsigned short Vs[2][512 * 32];     // 64.0 KB (linear, swz'd data)
    __shared__ unsigned short Ps[128 * 36];        //  9.2 KB  -> 139.2 KB

    const int d = blockIdx.x;                      // 0..255
    const int b    = ((d & 7) << 1) | (d >> 7);    // XCD j -> batches 2j,2j+1
    const int qblk = (d >> 3) & 15;                // 0..15
    const int t = threadIdx.x;
    const int w = t >> 6;                          // 0..7 : q-wave id
    const int l = t & 63, lr = l & 15, lg = l >> 4;
    const int vx = (lr >> 1) & 3;                  // V read-side slot XOR

    // ---- hoist Q fragments (pre-scaled by 1/sqrt(512)) ----
    bf16x8 q[16];
    {
        const unsigned short* qg =
            Qb + (size_t)(b * S_ + qblk * 128 + w * 16 + lr) * U_ + lg * 8;
        #pragma unroll
        for (int kc = 0; kc < 16; ++kc)
            q[kc] = *(const bf16x8*)(qg + kc * 32);
    }

    const unsigned short* kgb = Kb + (size_t)b * S_ * U_;
    const unsigned short* vgb = Vt + (size_t)b * U_ * S_;   // tile layout

    // stage tile kb into buffer buf via async DMA (8 wave-loads: 4 K + 4 V)
    #define STAGE(kb_, buf_)                                                    \
    do {                                                                        \
        const unsigned short* ksrc_ = kgb + (size_t)(kb_) * 32 * U_;            \
        const unsigned short* vsrc_ = vgb + (size_t)(kb_) * (512 * 32);         \
        _Pragma("unroll")                                                       \
        for (int i_ = 0; i_ < 4; ++i_) {                                        \
            const int r_ = w * 4 + i_;                                          \
            GL16(ksrc_ + (size_t)r_ * U_ + l * 8, &Ks[buf_][r_ * 516]);         \
        }                                                                       \
        _Pragma("unroll")                                                       \
        for (int i_ = 0; i_ < 4; ++i_) {                                        \
            const int c_ = w * 4 + i_;                                          \
            GL16(vsrc_ + c_ * 512 + l * 8, &Vs[buf_][c_ * 512]);                \
        }                                                                       \
    } while (0)

    // prologue: tile 0 -> buf 0
    STAGE(0, 0);
    asm volatile("s_waitcnt vmcnt(0)" ::: "memory");
    __builtin_amdgcn_s_barrier();
    __builtin_amdgcn_sched_barrier(0);

    f32x4 ctx[32];
    #pragma unroll
    for (int nt = 0; nt < 32; ++nt) ctx[nt] = (f32x4){0.f, 0.f, 0.f, 0.f};
    float m_i = -1e30f, l_i = 0.f;

    int cur = 0;
    for (int kb = 0; kb < S_ / 32; ++kb) {
        // ---- issue DMA for tile kb+1 into back buffer (overlaps compute) ----
        const int nkb = (kb + 1 < S_ / 32) ? kb + 1 : kb;
        STAGE(nkb, cur ^ 1);

        // ---- QK^T (swapped): S^T[key][q] from front buffer ----
        f32x4 s0 = (f32x4){0.f, 0.f, 0.f, 0.f};
        f32x4 s1 = (f32x4){0.f, 0.f, 0.f, 0.f};
        __builtin_amdgcn_s_setprio(1);
        #pragma unroll
        for (int kc = 0; kc < 16; ++kc) {
            const bf16x8 k0 = *(const bf16x8*)&Ks[cur][lr * 516 + kc * 32 + lg * 8];
            const bf16x8 k1 = *(const bf16x8*)&Ks[cur][(16 + lr) * 516 + kc * 32 + lg * 8];
            s0 = MFMA(k0, q[kc], s0);
            s1 = MFMA(k1, q[kc], s1);
        }
        __builtin_amdgcn_s_setprio(0);

        // ---- online softmax with deferred rescale (THR=8) ----
        float mb = s0[0];
        #pragma unroll
        for (int j = 1; j < 4; ++j) mb = fmaxf(mb, s0[j]);
        #pragma unroll
        for (int j = 0; j < 4; ++j) mb = fmaxf(mb, s1[j]);
        mb = fmaxf(mb, __shfl_xor(mb, 16));
        mb = fmaxf(mb, __shfl_xor(mb, 32));

        if (!__all(mb <= m_i + 8.f)) {
            const float m_new = fmaxf(m_i, mb);
            const float alpha = __expf(m_i - m_new);
            float arow[4];
            #pragma unroll
            for (int j = 0; j < 4; ++j)
                arow[j] = __shfl(alpha, (l & 48) | (lg * 4 + j));
            #pragma unroll
            for (int nt = 0; nt < 32; ++nt)
                #pragma unroll
                for (int j = 0; j < 4; ++j) ctx[nt][j] *= arow[j];
            l_i *= alpha;
            m_i = m_new;
        }

        float p0[4], p1[4];
        float ladd = 0.f;
        #pragma unroll
        for (int j = 0; j < 4; ++j) {
            p0[j] = __expf(s0[j] - m_i);
            p1[j] = __expf(s1[j] - m_i);
            ladd += p0[j] + p1[j];
        }
        ladd += __shfl_xor(ladd, 16);
        ladd += __shfl_xor(ladd, 32);
        l_i += ladd;

        // ---- P -> A-fragment layout via wave-private LDS rows ----
        us4 w0, w1;
        w0.x = f2b(p0[0]); w0.y = f2b(p0[1]); w0.z = f2b(p0[2]); w0.w = f2b(p0[3]);
        w1.x = f2b(p1[0]); w1.y = f2b(p1[1]); w1.z = f2b(p1[2]); w1.w = f2b(p1[3]);
        *(us4*)&Ps[(w * 16 + lr) * 36 + lg * 4]      = w0;
        *(us4*)&Ps[(w * 16 + lr) * 36 + 16 + lg * 4] = w1;
        const bf16x8 pf = *(const bf16x8*)&Ps[(w * 16 + lr) * 36 + lg * 8];

        // ---- PV over full 512 u (swizzled V read) ----
        __builtin_amdgcn_s_setprio(1);
        #pragma unroll
        for (int nt = 0; nt < 32; ++nt) {
            const bf16x8 vf =
                *(const bf16x8*)&Vs[cur][(nt * 16 + lr) * 32 + ((lg ^ vx) * 8)];
            ctx[nt] = MFMA(pf, vf, ctx[nt]);
        }
        __builtin_amdgcn_s_setprio(0);

        // ---- single sync point: next tile landed, all waves done reading ----
        asm volatile("s_waitcnt vmcnt(0)" ::: "memory");
        __builtin_amdgcn_s_barrier();
        __builtin_amdgcn_sched_barrier(0);
        cur ^= 1;
    }

    // ---- epilogue: normalize, sum wave's 16 queries, combine 8 waves ----
    const float inv = 1.f / l_i;
    float invr[4];
    #pragma unroll
    for (int j = 0; j < 4; ++j)
        invr[j] = __shfl(inv, (l & 48) | (lg * 4 + j));

    float* SumBuf = (float*)&Ks[0][0];     // alias (loop done, DMA drained)
    #pragma unroll
    for (int nt = 0; nt < 32; ++nt) {
        float s = ctx[nt][0] * invr[0] + ctx[nt][1] * invr[1]
                + ctx[nt][2] * invr[2] + ctx[nt][3] * invr[3];
        s += __shfl_xor(s, 16);
        s += __shfl_xor(s, 32);
        if (lg == 0) SumBuf[w * 512 + nt * 16 + lr] = s;
    }
    __syncthreads();
    {
        const int u = t;                       // 512 threads cover 512 u
        float s = 0.f;
        #pragma unroll
        for (int ww = 0; ww < 8; ++ww) s += SumBuf[ww * 512 + u];
        partial[(size_t)(b * 16 + qblk) * U_ + u] = s;
    }
    #undef STAGE
}

// ---------------------------------------------------------------------------
// partial [16][16][512] -> out [16][512], mean over S
// ---------------------------------------------------------------------------
__global__ __launch_bounds__(256) void reduce_mean(
    const float* __restrict__ partial, float* __restrict__ out)
{
    const int b = blockIdx.x;
    for (int u = threadIdx.x; u < U_; u += 256) {
        float s = 0.f;
        #pragma unroll
        for (int p = 0; p < 16; ++p)
            s += partial[(size_t)(b * 16 + p) * U_ + u];
        out[b * U_ + u] = s * (1.0f / (float)S_);
    }
}

extern "C" void kernel_launch(void* const* d_in, const int* in_sizes, int n_in,
                              void* d_out, int out_size, void* d_ws, size_t ws_size,
                              hipStream_t stream)
{
    const float* x  = (const float*)d_in[0];
    const float* Wq = (const float*)d_in[1];
    const float* Wk = (const float*)d_in[2];
    const float* Wv = (const float*)d_in[3];
    float* out = (float*)d_out;

    unsigned short* ws = (unsigned short*)d_ws;
    const size_t XB_OFF = 0;                               // [32768][512] bf16
    const size_t WT_OFF = XB_OFF + (size_t)NROWS * F_;     // 3x[512][512] bf16
    const size_t QB_OFF = WT_OFF + 3ull * F_ * U_;
    const size_t KB_OFF = QB_OFF + (size_t)NROWS * U_;
    const size_t VT_OFF = KB_OFF + (size_t)NROWS * U_;
    const size_t END_USH = VT_OFF + (size_t)NROWS * U_;
    float* partial = (float*)(ws + END_USH);               // [16][16][512] fp32
    const size_t need = END_USH * 2 + (size_t)B_ * 16 * U_ * 4;
    if (ws_size < need) return;

    unsigned short* xb = ws + XB_OFF;
    unsigned short* Wt = ws + WT_OFF;
    unsigned short* Qb = ws + QB_OFF;
    unsigned short* Kb = ws + KB_OFF;
    unsigned short* Vt = ws + VT_OFF;

    conv_x<<<2048, 256, 0, stream>>>(x, xb);
    conv_w<<<dim3(16, 16, 3), 256, 0, stream>>>(Wq, Wk, Wv, Wt);
    qkv_gemm<<<dim3(NROWS / 128, U_ / 64, 3), 256, 0, stream>>>(xb, Wt, Qb, Kb, Vt);
    attn_mfma<<<256, 512, 0, stream>>>(Qb, Kb, Vt, partial);
    reduce_mean<<<B_, 256, 0, stream>>>(partial, out);
}

// Round 10
// 294.383 us; speedup vs baseline: 6.9213x; 1.9205x over previous
//
#include <hip/hip_runtime.h>

typedef short bf16x8 __attribute__((ext_vector_type(8)));
typedef float f32x4 __attribute__((ext_vector_type(4)));
typedef unsigned short us4 __attribute__((ext_vector_type(4)));

#define B_ 16
#define S_ 2048
#define F_ 512
#define U_ 512
#define NROWS (B_ * S_)          // 32768

#define MFMA(a, b, c) __builtin_amdgcn_mfma_f32_16x16x32_bf16((a), (b), (c), 0, 0, 0)

// async global->LDS, 16B per lane; LDS dest = uniform base + lane*16
#define GL16(g, s) __builtin_amdgcn_global_load_lds( \
    (const __attribute__((address_space(1))) unsigned int*)(g), \
    (__attribute__((address_space(3))) unsigned int*)(s), 16, 0, 0)

__device__ __forceinline__ unsigned short f2b(float f) {
    unsigned u = __builtin_bit_cast(unsigned, f);
    return (unsigned short)((u + 0x7FFFu + ((u >> 16) & 1u)) >> 16);
}

// ---------------------------------------------------------------------------
// x fp32 -> bf16 row-major [32768][512]
// ---------------------------------------------------------------------------
__global__ __launch_bounds__(256) void conv_x(const float* __restrict__ x,
                                              unsigned short* __restrict__ xb)
{
    const size_t n8 = (size_t)NROWS * F_ / 8;
    const size_t stride = (size_t)gridDim.x * 256;
    for (size_t i = (size_t)blockIdx.x * 256 + threadIdx.x; i < n8; i += stride) {
        const float4 a = ((const float4*)x)[i * 2];
        const float4 b = ((const float4*)x)[i * 2 + 1];
        us4 lo, hi;
        lo.x = f2b(a.x); lo.y = f2b(a.y); lo.z = f2b(a.z); lo.w = f2b(a.w);
        hi.x = f2b(b.x); hi.y = f2b(b.y); hi.z = f2b(b.z); hi.w = f2b(b.w);
        ((us4*)xb)[i * 2]     = lo;
        ((us4*)xb)[i * 2 + 1] = hi;
    }
}

// ---------------------------------------------------------------------------
// W [k][n] fp32 -> Wt [z][n][k] bf16 (transposed)
// ---------------------------------------------------------------------------
__global__ __launch_bounds__(256) void conv_w(const float* __restrict__ Wq,
                                              const float* __restrict__ Wk,
                                              const float* __restrict__ Wv,
                                              unsigned short* __restrict__ Wt)
{
    const float* W = (blockIdx.z == 0) ? Wq : (blockIdx.z == 1) ? Wk : Wv;
    unsigned short* out = Wt + (size_t)blockIdx.z * F_ * U_;
    __shared__ float tile[32][33];
    const int k0 = blockIdx.x * 32, n0 = blockIdx.y * 32;
    const int r = threadIdx.x >> 5, c = threadIdx.x & 31;
    #pragma unroll
    for (int p = 0; p < 4; ++p)
        tile[p * 8 + r][c] = W[(size_t)(k0 + p * 8 + r) * U_ + n0 + c];
    __syncthreads();
    #pragma unroll
    for (int p = 0; p < 4; ++p)
        out[(size_t)(n0 + p * 8 + r) * F_ + k0 + c] = f2b(tile[c][p * 8 + r]);
}

// ---------------------------------------------------------------------------
// QKV GEMM, bf16 MFMA 16x16x32.  Tile 128x64, 4 waves, BK=32.
// z=0 -> Qb (pre-scaled by 1/sqrt(512)), z=1 -> Kb row-major,
// z=2 -> Vt TILE-layout [b][tile=s/32][u][32 k] with slot XOR pre-swizzle
//        (slot' = slot ^ ((u>>1)&3)) so attention can DMA it linearly.
// ---------------------------------------------------------------------------
__global__ __launch_bounds__(256) void qkv_gemm(
    const unsigned short* __restrict__ xb,
    const unsigned short* __restrict__ Wt,
    unsigned short* __restrict__ Qb,
    unsigned short* __restrict__ Kb,
    unsigned short* __restrict__ Vt)
{
    __shared__ char smem[128 * 65 * 4];                 // 33280 B
    unsigned short* Xs = (unsigned short*)smem;         // [128][32] swizzled
    unsigned short* Ws = Xs + 128 * 32;                 // [64][32]  swizzled
    float* Cs = (float*)smem;                           // [128][65]

    const int z = blockIdx.z;
    const unsigned short* Wz = Wt + (size_t)z * F_ * U_;
    const int bm = blockIdx.x * 128;
    const int bn = blockIdx.y * 64;
    const int t = threadIdx.x;
    const int w = t >> 6, l = t & 63, lr = l & 15, lg = l >> 4;
    const int vxA = (lr >> 1) & 3;       // read-side slot XOR

    f32x4 acc[2][4];
    #pragma unroll
    for (int mt = 0; mt < 2; ++mt)
        #pragma unroll
        for (int nt = 0; nt < 4; ++nt)
            acc[mt][nt] = (f32x4){0.f, 0.f, 0.f, 0.f};

    for (int kc = 0; kc < 16; ++kc) {
        const int k0 = kc * 32;
        __syncthreads();
        #pragma unroll
        for (int p = 0; p < 2; ++p) {
            const int idx = p * 256 + t;
            const int row = idx >> 2, slot = idx & 3;
            const bf16x8 v =
                *(const bf16x8*)&xb[(size_t)(bm + row) * F_ + k0 + slot * 8];
            *(bf16x8*)&Xs[row * 32 + ((slot ^ ((row >> 1) & 3)) * 8)] = v;
        }
        {
            const int row = t >> 2, slot = t & 3;
            const bf16x8 v =
                *(const bf16x8*)&Wz[(size_t)(bn + row) * F_ + k0 + slot * 8];
            *(bf16x8*)&Ws[row * 32 + ((slot ^ ((row >> 1) & 3)) * 8)] = v;
        }
        __syncthreads();
        const bf16x8 a0 = *(const bf16x8*)&Xs[(w * 32 + lr) * 32 + ((lg ^ vxA) * 8)];
        const bf16x8 a1 = *(const bf16x8*)&Xs[(w * 32 + 16 + lr) * 32 + ((lg ^ vxA) * 8)];
        #pragma unroll
        for (int nt = 0; nt < 4; ++nt) {
            const bf16x8 bb = *(const bf16x8*)&Ws[(nt * 16 + lr) * 32 + ((lg ^ vxA) * 8)];
            acc[0][nt] = MFMA(a0, bb, acc[0][nt]);
            acc[1][nt] = MFMA(a1, bb, acc[1][nt]);
        }
    }
    __syncthreads();
    #pragma unroll
    for (int mt = 0; mt < 2; ++mt)
        #pragma unroll
        for (int nt = 0; nt < 4; ++nt)
            #pragma unroll
            for (int j = 0; j < 4; ++j)
                Cs[(w * 32 + mt * 16 + lg * 4 + j) * 65 + nt * 16 + lr] = acc[mt][nt][j];
    __syncthreads();

    if (z < 2) {
        unsigned short* out = (z == 0) ? Qb : Kb;
        const float qs = (z == 0) ? 0.044194173824159216f : 1.0f;  // 1/sqrt(512)
        const int row = t >> 1, half = t & 1;
        unsigned short tmp[32];
        #pragma unroll
        for (int i = 0; i < 32; ++i) tmp[i] = f2b(Cs[row * 65 + half * 32 + i] * qs);
        #pragma unroll
        for (int v = 0; v < 4; ++v)
            *(bf16x8*)&out[(size_t)(bm + row) * U_ + bn + half * 32 + v * 8] =
                *(bf16x8*)&tmp[v * 8];
    } else {
        // V tile-layout write: Vt[b][tile][u][32], slot XOR pre-swizzled
        const int c = t >> 2, s0 = (t & 3) * 32;       // s0 multiple of 32
        const int b = bm >> 11, sbase = (bm & 2047) + s0;
        const int u = bn + c;
        const int tile = sbase >> 5;
        const int vx = (u >> 1) & 3;
        unsigned short tmp[32];
        #pragma unroll
        for (int i = 0; i < 32; ++i) tmp[i] = f2b(Cs[(s0 + i) * 65 + c]);
        unsigned short* vdst =
            Vt + (size_t)b * U_ * S_ + (size_t)tile * (512 * 32) + u * 32;
        #pragma unroll
        for (int v = 0; v < 4; ++v)
            *(bf16x8*)&vdst[(v ^ vx) * 8] = *(bf16x8*)&tmp[v * 8];
    }
}

// ---------------------------------------------------------------------------
// Flash attention v10 = R5 wave structure (8 independent q-waves, 16q x 512u,
// ctx 32 f32x4) + global_load_lds DMA double-buffer, but with PLAIN
// __syncthreads() as the only sync (compiler emits the vmcnt drain itself).
// No inline asm, no sched_barrier, no setprio -- isolates DMA staging.
//   loop: STAGE(kb+1 -> back)  [async DMA, overlaps compute below]
//         compute tile kb from front
//         __syncthreads()      [drains DMA + orders LDS]
// ---------------------------------------------------------------------------
__global__ __launch_bounds__(512, 2) void attn_mfma(
    const unsigned short* __restrict__ Qb,
    const unsigned short* __restrict__ Kb,
    const unsigned short* __restrict__ Vt,
    float* __restrict__ partial)
{
    __shared__ unsigned short Ks[2][32 * 516];     // 66.0 KB (rows 1032B)
    __shared__ unsigned short Vs[2][512 * 32];     // 64.0 KB (linear, swz'd data)
    __shared__ unsigned short Ps[128 * 36];        //  9.2 KB  -> 139.2 KB

    const int d = blockIdx.x;                      // 0..255
    const int b    = ((d & 7) << 1) | (d >> 7);    // XCD j -> batches 2j,2j+1
    const int qblk = (d >> 3) & 15;                // 0..15
    const int t = threadIdx.x;
    const int w = t >> 6;                          // 0..7 : q-wave id
    const int l = t & 63, lr = l & 15, lg = l >> 4;
    const int vx = (lr >> 1) & 3;                  // V read-side slot XOR

    // ---- hoist Q fragments (pre-scaled by 1/sqrt(512)) ----
    bf16x8 q[16];
    {
        const unsigned short* qg =
            Qb + (size_t)(b * S_ + qblk * 128 + w * 16 + lr) * U_ + lg * 8;
        #pragma unroll
        for (int kc = 0; kc < 16; ++kc)
            q[kc] = *(const bf16x8*)(qg + kc * 32);
    }

    const unsigned short* kgb = Kb + (size_t)b * S_ * U_;
    const unsigned short* vgb = Vt + (size_t)b * U_ * S_;   // tile layout

    // stage tile kb into buffer buf via async DMA (8 wave-loads: 4 K + 4 V)
    #define STAGE(kb_, buf_)                                                    \
    do {                                                                        \
        const unsigned short* ksrc_ = kgb + (size_t)(kb_) * 32 * U_;            \
        const unsigned short* vsrc_ = vgb + (size_t)(kb_) * (512 * 32);         \
        _Pragma("unroll")                                                       \
        for (int i_ = 0; i_ < 4; ++i_) {                                        \
            const int r_ = w * 4 + i_;                                          \
            GL16(ksrc_ + (size_t)r_ * U_ + l * 8, &Ks[buf_][r_ * 516]);         \
        }                                                                       \
        _Pragma("unroll")                                                       \
        for (int i_ = 0; i_ < 4; ++i_) {                                        \
            const int c_ = w * 4 + i_;                                          \
            GL16(vsrc_ + c_ * 512 + l * 8, &Vs[buf_][c_ * 512]);                \
        }                                                                       \
    } while (0)

    // prologue: tile 0 -> buf 0
    STAGE(0, 0);
    __syncthreads();

    f32x4 ctx[32];
    #pragma unroll
    for (int nt = 0; nt < 32; ++nt) ctx[nt] = (f32x4){0.f, 0.f, 0.f, 0.f};
    float m_i = -1e30f, l_i = 0.f;

    int cur = 0;
    for (int kb = 0; kb < S_ / 32; ++kb) {
        // ---- issue DMA for tile kb+1 into back buffer (overlaps compute) ----
        const int nkb = (kb + 1 < S_ / 32) ? kb + 1 : kb;
        STAGE(nkb, cur ^ 1);

        // ---- QK^T (swapped): S^T[key][q] from front buffer ----
        f32x4 s0 = (f32x4){0.f, 0.f, 0.f, 0.f};
        f32x4 s1 = (f32x4){0.f, 0.f, 0.f, 0.f};
        #pragma unroll
        for (int kc = 0; kc < 16; ++kc) {
            const bf16x8 k0 = *(const bf16x8*)&Ks[cur][lr * 516 + kc * 32 + lg * 8];
            const bf16x8 k1 = *(const bf16x8*)&Ks[cur][(16 + lr) * 516 + kc * 32 + lg * 8];
            s0 = MFMA(k0, q[kc], s0);
            s1 = MFMA(k1, q[kc], s1);
        }

        // ---- online softmax with deferred rescale (THR=8) ----
        float mb = s0[0];
        #pragma unroll
        for (int j = 1; j < 4; ++j) mb = fmaxf(mb, s0[j]);
        #pragma unroll
        for (int j = 0; j < 4; ++j) mb = fmaxf(mb, s1[j]);
        mb = fmaxf(mb, __shfl_xor(mb, 16));
        mb = fmaxf(mb, __shfl_xor(mb, 32));

        if (!__all(mb <= m_i + 8.f)) {
            const float m_new = fmaxf(m_i, mb);
            const float alpha = __expf(m_i - m_new);
            float arow[4];
            #pragma unroll
            for (int j = 0; j < 4; ++j)
                arow[j] = __shfl(alpha, (l & 48) | (lg * 4 + j));
            #pragma unroll
            for (int nt = 0; nt < 32; ++nt)
                #pragma unroll
                for (int j = 0; j < 4; ++j) ctx[nt][j] *= arow[j];
            l_i *= alpha;
            m_i = m_new;
        }

        float p0[4], p1[4];
        float ladd = 0.f;
        #pragma unroll
        for (int j = 0; j < 4; ++j) {
            p0[j] = __expf(s0[j] - m_i);
            p1[j] = __expf(s1[j] - m_i);
            ladd += p0[j] + p1[j];
        }
        ladd += __shfl_xor(ladd, 16);
        ladd += __shfl_xor(ladd, 32);
        l_i += ladd;

        // ---- P -> A-fragment layout via wave-private LDS rows ----
        us4 w0, w1;
        w0.x = f2b(p0[0]); w0.y = f2b(p0[1]); w0.z = f2b(p0[2]); w0.w = f2b(p0[3]);
        w1.x = f2b(p1[0]); w1.y = f2b(p1[1]); w1.z = f2b(p1[2]); w1.w = f2b(p1[3]);
        *(us4*)&Ps[(w * 16 + lr) * 36 + lg * 4]      = w0;
        *(us4*)&Ps[(w * 16 + lr) * 36 + 16 + lg * 4] = w1;
        const bf16x8 pf = *(const bf16x8*)&Ps[(w * 16 + lr) * 36 + lg * 8];

        // ---- PV over full 512 u (swizzled V read) ----
        #pragma unroll
        for (int nt = 0; nt < 32; ++nt) {
            const bf16x8 vf =
                *(const bf16x8*)&Vs[cur][(nt * 16 + lr) * 32 + ((lg ^ vx) * 8)];
            ctx[nt] = MFMA(pf, vf, ctx[nt]);
        }

        // ---- single sync: drains next-tile DMA, orders all LDS access ----
        __syncthreads();
        cur ^= 1;
    }

    // ---- epilogue: normalize, sum wave's 16 queries, combine 8 waves ----
    const float inv = 1.f / l_i;
    float invr[4];
    #pragma unroll
    for (int j = 0; j < 4; ++j)
        invr[j] = __shfl(inv, (l & 48) | (lg * 4 + j));

    float* SumBuf = (float*)&Ks[0][0];     // alias (loop done, DMA drained)
    #pragma unroll
    for (int nt = 0; nt < 32; ++nt) {
        float s = ctx[nt][0] * invr[0] + ctx[nt][1] * invr[1]
                + ctx[nt][2] * invr[2] + ctx[nt][3] * invr[3];
        s += __shfl_xor(s, 16);
        s += __shfl_xor(s, 32);
        if (lg == 0) SumBuf[w * 512 + nt * 16 + lr] = s;
    }
    __syncthreads();
    {
        const int u = t;                       // 512 threads cover 512 u
        float s = 0.f;
        #pragma unroll
        for (int ww = 0; ww < 8; ++ww) s += SumBuf[ww * 512 + u];
        partial[(size_t)(b * 16 + qblk) * U_ + u] = s;
    }
    #undef STAGE
}

// ---------------------------------------------------------------------------
// partial [16][16][512] -> out [16][512], mean over S
// ---------------------------------------------------------------------------
__global__ __launch_bounds__(256) void reduce_mean(
    const float* __restrict__ partial, float* __restrict__ out)
{
    const int b = blockIdx.x;
    for (int u = threadIdx.x; u < U_; u += 256) {
        float s = 0.f;
        #pragma unroll
        for (int p = 0; p < 16; ++p)
            s += partial[(size_t)(b * 16 + p) * U_ + u];
        out[b * U_ + u] = s * (1.0f / (float)S_);
    }
}

extern "C" void kernel_launch(void* const* d_in, const int* in_sizes, int n_in,
                              void* d_out, int out_size, void* d_ws, size_t ws_size,
                              hipStream_t stream)
{
    const float* x  = (const float*)d_in[0];
    const float* Wq = (const float*)d_in[1];
    const float* Wk = (const float*)d_in[2];
    const float* Wv = (const float*)d_in[3];
    float* out = (float*)d_out;

    unsigned short* ws = (unsigned short*)d_ws;
    const size_t XB_OFF = 0;                               // [32768][512] bf16
    const size_t WT_OFF = XB_OFF + (size_t)NROWS * F_;     // 3x[512][512] bf16
    const size_t QB_OFF = WT_OFF + 3ull * F_ * U_;
    const size_t KB_OFF = QB_OFF + (size_t)NROWS * U_;
    const size_t VT_OFF = KB_OFF + (size_t)NROWS * U_;
    const size_t END_USH = VT_OFF + (size_t)NROWS * U_;
    float* partial = (float*)(ws + END_USH);               // [16][16][512] fp32
    const size_t need = END_USH * 2 + (size_t)B_ * 16 * U_ * 4;
    if (ws_size < need) return;

    unsigned short* xb = ws + XB_OFF;
    unsigned short* Wt = ws + WT_OFF;
    unsigned short* Qb = ws + QB_OFF;
    unsigned short* Kb = ws + KB_OFF;
    unsigned short* Vt = ws + VT_OFF;

    conv_x<<<2048, 256, 0, stream>>>(x, xb);
    conv_w<<<dim3(16, 16, 3), 256, 0, stream>>>(Wq, Wk, Wv, Wt);
    qkv_gemm<<<dim3(NROWS / 128, U_ / 64, 3), 256, 0, stream>>>(xb, Wt, Qb, Kb, Vt);
    attn_mfma<<<256, 512, 0, stream>>>(Qb, Kb, Vt, partial);
    reduce_mean<<<B_, 256, 0, stream>>>(partial, out);
}